// Round 10
// baseline (1967.837 us; speedup 1.0000x reference)
//
#include <hip/hip_runtime.h>
#include <math.h>

#define Bsz 8192
#define Hd  512
#define Vd  512
#define Ld  16
#define G4  2048   // 4*Hd
#define NSLAB 16   // 32-col vocab slabs

using short8 = __attribute__((ext_vector_type(8))) short;
using f32x4  = __attribute__((ext_vector_type(4))) float;
using int4v  = __attribute__((ext_vector_type(4))) int;

__device__ __forceinline__ float sigm_f(float x){
  return __builtin_amdgcn_rcpf(1.0f + __expf(-x));
}
__device__ __forceinline__ float tanh_f(float x){
  return 1.0f - 2.0f * __builtin_amdgcn_rcpf(1.0f + __expf(2.0f * x));
}

// bf16 bit helpers (RNE)
__device__ __forceinline__ unsigned short f2bf(float f){
  unsigned int u = __float_as_uint(f);
  u = (u + 0x7fffu + ((u >> 16) & 1u)) >> 16;
  return (unsigned short)u;
}
__device__ __forceinline__ float bf2f(unsigned short b){
  return __uint_as_float(((unsigned int)b) << 16);
}

// int16 -> signed i8 pair: q = 256*a + b, a,b in [-128,127]
__device__ __forceinline__ void i16split(float x, float S, signed char& a, signed char& b){
  int q = (int)rintf(x * S);
  q = min(max(q, -32640), 32639);
  const int ah = (q + 128) >> 8;
  a = (signed char)ah;
  b = (signed char)(q - (ah << 8));
}

__device__ __forceinline__ void gl_lds16(const void* g, void* l){
  __builtin_amdgcn_global_load_lds((const __attribute__((address_space(1))) void*)g,
                                   (__attribute__((address_space(3))) void*)l, 16, 0, 0);
}

// reconstruction constants: value = (65536*acc1 + 256*acc2) / (2^19 * 32767)
#define C1I (65536.0f / (524288.0f * 32767.0f))
#define C2I (  256.0f / (524288.0f * 32767.0f))

// ---------------------------------------------------------------------------
// Transpose W_ih (2048 x 512) -> W_ihT (512 x 2048): one-hot gather rows.
// ---------------------------------------------------------------------------
__global__ __launch_bounds__(256) void k_transpose(const float* __restrict__ in,
                                                   float* __restrict__ out){
  __shared__ float tile[32][33];
  const int tx = threadIdx.x, ty = threadIdx.y;
  const int v0 = blockIdx.x * 32, n0 = blockIdx.y * 32;
#pragma unroll
  for(int i=0;i<4;i++)
    tile[ty+i*8][tx] = in[(size_t)(n0+ty+i*8)*Vd + v0+tx];
  __syncthreads();
#pragma unroll
  for(int i=0;i<4;i++)
    out[(size_t)(v0+ty+i*8)*G4 + n0+tx] = tile[tx][ty+i*8];
}

// ---------------------------------------------------------------------------
// Split fp32 -> (bf16 hi, bf16 lo)   [step-0 path only]
// ---------------------------------------------------------------------------
__global__ __launch_bounds__(256) void k_split(const float* __restrict__ src,
                                               unsigned short* __restrict__ hi,
                                               unsigned short* __restrict__ lo, int n){
  const int i = blockIdx.x*256 + threadIdx.x;
  if(i < n){
    const float x = src[i];
    const unsigned short h = f2bf(x);
    hi[i] = h;
    lo[i] = f2bf(x - bf2f(h));
  }
}

// ---------------------------------------------------------------------------
// Split fp32 -> int16 fixed-point -> i8 planes
// ---------------------------------------------------------------------------
__global__ __launch_bounds__(256) void k_split_i8(const float* __restrict__ src,
                                                  signed char* __restrict__ pa,
                                                  signed char* __restrict__ pb,
                                                  float S, int n){
  const int i = blockIdx.x*256 + threadIdx.x;
  if(i < n){
    signed char a, b;
    i16split(src[i], S, a, b);
    pa[i] = a; pb[i] = b;
  }
}

// ---------------------------------------------------------------------------
// Kernel A0 (step 0 only): bf16x2 3-product MFMA LSTM step from enc_h.
// (LDS double-buffered version — runs once, not worth rewriting.)
// ---------------------------------------------------------------------------
__global__ __launch_bounds__(256, 2) void k_lstm_bf16(
    const unsigned short* __restrict__ hh, const unsigned short* __restrict__ hl,
    const float* __restrict__ cin,
    signed char* __restrict__ ha, signed char* __restrict__ hb,
    float* __restrict__ cout,
    const unsigned short* __restrict__ Whh_hi, const unsigned short* __restrict__ Whh_lo,
    const float* __restrict__ bih, const float* __restrict__ bhh)
{
  __shared__ unsigned short lds[2][16384];
  const int tid = threadIdx.x;
  const int wave = tid >> 6, lane = tid & 63;
  const int mb = blockIdx.x * 128;
  const int jb = blockIdx.y * 32;
  const int b_wave = (wave & 1) * 64;
  const int j_wave = (wave >> 1) * 16;
  const int fr = lane & 15, q = lane >> 4;
  const int lr = lane >> 2, jj = lane & 3;

  auto stage = [&](int k0, int bsel){
    unsigned short* Whi = lds[bsel];
    unsigned short* Wlo = lds[bsel] + 4096;
    unsigned short* Hhi = lds[bsel] + 8192;
    unsigned short* Hlo = lds[bsel] + 12288;
#pragma unroll
    for(int p=0;p<2;p++){
      const int s = wave*2 + p;
      const int r = s*16 + lr;
      const int j = jj ^ ((r >> 1) & 3);
      const size_t ka = (size_t)k0 + j*8;
      const size_t wrow = (size_t)((r >> 5)*Hd + jb + (r & 31));
      gl_lds16(Whh_hi + wrow*Hd + ka, &Whi[s*512]);
      gl_lds16(Whh_lo + wrow*Hd + ka, &Wlo[s*512]);
      gl_lds16(hh + (size_t)(mb + r)*Hd + ka, &Hhi[s*512]);
      gl_lds16(hl + (size_t)(mb + r)*Hd + ka, &Hlo[s*512]);
    }
  };

  stage(0, 0);

  const int j0 = jb + j_wave + q*4;
  float bsum[4][4];
#pragma unroll
  for(int g=0;g<4;g++){
    float4 a = *(const float4*)&bih[g*Hd + j0];
    float4 b = *(const float4*)&bhh[g*Hd + j0];
    bsum[g][0]=a.x+b.x; bsum[g][1]=a.y+b.y; bsum[g][2]=a.z+b.z; bsum[g][3]=a.w+b.w;
  }

  f32x4 acc[4][4];
#pragma unroll
  for(int g=0;g<4;g++)
#pragma unroll
    for(int bt=0;bt<4;bt++) acc[g][bt] = (f32x4){0.f,0.f,0.f,0.f};

  for(int kc=0; kc<16; kc++){
    __syncthreads();
    if(kc < 15) stage((kc+1)*32, (kc+1)&1);

    const unsigned short* Whi = lds[kc&1];
    const unsigned short* Wlo = lds[kc&1] + 4096;
    const unsigned short* Hhi = lds[kc&1] + 8192;
    const unsigned short* Hlo = lds[kc&1] + 12288;

    short8 wh[4], wl[4], hf[4], lf[4];
#pragma unroll
    for(int g=0;g<4;g++){
      const int r = g*32 + j_wave + fr;
      const int off = r*32 + ((q ^ ((r >> 1) & 3)) << 3);
      wh[g] = *(const short8*)&Whi[off];
      wl[g] = *(const short8*)&Wlo[off];
    }
#pragma unroll
    for(int bt=0;bt<4;bt++){
      const int r = b_wave + bt*16 + fr;
      const int off = r*32 + ((q ^ ((r >> 1) & 3)) << 3);
      hf[bt] = *(const short8*)&Hhi[off];
      lf[bt] = *(const short8*)&Hlo[off];
    }
#pragma unroll
    for(int g=0;g<4;g++)
#pragma unroll
      for(int bt=0;bt<4;bt++){
        acc[g][bt] = __builtin_amdgcn_mfma_f32_16x16x32_bf16(wh[g], hf[bt], acc[g][bt], 0,0,0);
        acc[g][bt] = __builtin_amdgcn_mfma_f32_16x16x32_bf16(wh[g], lf[bt], acc[g][bt], 0,0,0);
        acc[g][bt] = __builtin_amdgcn_mfma_f32_16x16x32_bf16(wl[g], hf[bt], acc[g][bt], 0,0,0);
      }
  }

#pragma unroll
  for(int bt=0;bt<4;bt++){
    const int b = mb + b_wave + bt*16 + fr;
    const size_t idx = (size_t)b*Hd + j0;
    float gv[4][4];
#pragma unroll
    for(int g=0;g<4;g++)
#pragma unroll
      for(int r=0;r<4;r++) gv[g][r] = acc[g][bt][r] + bsum[g][r];
    float co[4];
    *(float4*)co = *(const float4*)&cin[idx];
    float cn[4];
    signed char a4[4], b4[4];
#pragma unroll
    for(int r=0;r<4;r++){
      const float I = sigm_f(gv[0][r]);
      const float F = sigm_f(gv[1][r]);
      const float G = tanh_f(gv[2][r]);
      const float O = sigm_f(gv[3][r]);
      cn[r] = F*co[r] + I*G;
      const float hn = O*tanh_f(cn[r]);
      i16split(hn, 32767.0f, a4[r], b4[r]);
    }
    *(float4*)&cout[idx] = *(float4*)cn;
    *(char4*)&ha[idx] = *(char4*)a4;
    *(char4*)&hb[idx] = *(char4*)b4;
  }
}

// ---------------------------------------------------------------------------
// Kernel A (steps >=1): i8 LSTM step, BARRIER-FREE K-loop.
// MFMA fragments are 16 contiguous bytes of a global row -> load them
// directly to VGPRs (buffer_load_dwordx4). No LDS staging, no __syncthreads
// in the K-loop; latency hidden by 8 waves/CU + compiler vmcnt pipelining.
// Merge prologue for prev step unchanged (kernel-boundary visibility).
// ---------------------------------------------------------------------------
__global__ __launch_bounds__(256, 2) void k_lstm_i8(
    const signed char* __restrict__ hA, const signed char* __restrict__ hB,
    const float* __restrict__ cin,
    signed char* __restrict__ hoA, signed char* __restrict__ hoB,
    float* __restrict__ cout,
    const signed char* __restrict__ WA, const signed char* __restrict__ WB,
    const float* __restrict__ WihT, const float* __restrict__ bih,
    const float* __restrict__ bhh,
    const float* __restrict__ statM, const float* __restrict__ statS,
    const int* __restrict__ statI,
    float* __restrict__ msg, float* __restrict__ masks_out,
    float* __restrict__ lp_out, float* __restrict__ lpbuf,
    float* __restrict__ mbuf, int prev)
{
  __shared__ int gIs[128];
  const int tid = threadIdx.x;
  const int wave = tid >> 6, lane = tid & 63;
  const int mb = blockIdx.x * 128;
  const int jb = blockIdx.y * 32;
  const int b_wave = (wave & 1) * 64;
  const int j_wave = (wave >> 1) * 16;
  const int fr = lane & 15, q = lane >> 4;

  // ---- merge prologue: prev-step stats -> gi per row (+ scalar outputs)
  if(tid < 128){
    const int row = mb + tid;
    float gm = statM[row]; int gi = statI[row];
#pragma unroll
    for(int s=1;s<NSLAB;s++){
      const float m = statM[(size_t)s*Bsz + row];
      if(m > gm){ gm = m; gi = statI[(size_t)s*Bsz + row]; }
    }
    if(blockIdx.y == 0){
      float tot = 0.0f;
#pragma unroll
      for(int s=0;s<NSLAB;s++)
        tot += statS[(size_t)s*Bsz + row] * __expf(statM[(size_t)s*Bsz + row] - gm);
      const float logp = -__logf(tot);
      const float mo  = (prev == 0) ? 1.0f : mbuf[row];
      const float lpo = (prev == 0) ? 0.0f : lpbuf[row];
      const float lpn = lpo + logp * mo;
      masks_out[(size_t)prev * Bsz + row] = mo;
      lp_out[row] = lpn;
      lpbuf[row]  = lpn;
      mbuf[row]   = mo * ((gi == Vd-1) ? 0.0f : 1.0f);
    }
    gIs[tid] = gi;
  }
  __syncthreads();

  // one-hot msg slice: this block writes cols [jb, jb+32) of prev-step msg
  {
    const int r  = tid >> 1;
    const int c0 = jb + (tid & 1) * 16;
    const int gi = gIs[r];
    float* mrow = msg + ((size_t)prev * Bsz + mb + r) * Vd;
#pragma unroll
    for(int i=0;i<4;i++){
      const int c = c0 + i*4;
      float4 v;
      v.x = (c   == gi) ? 1.0f : 0.0f;
      v.y = (c+1 == gi) ? 1.0f : 0.0f;
      v.z = (c+2 == gi) ? 1.0f : 0.0f;
      v.w = (c+3 == gi) ? 1.0f : 0.0f;
      *(float4*)&mrow[c] = v;
    }
  }

  int xid[4];
#pragma unroll
  for(int bt=0;bt<4;bt++)
    xid[bt] = gIs[b_wave + bt*16 + fr];

  // ---- row base offsets (constant over K)
  size_t wro[4], hro[4];
#pragma unroll
  for(int g=0;g<4;g++)
    wro[g] = (size_t)(g*Hd + jb + j_wave + fr)*Hd + q*16;
#pragma unroll
  for(int bt=0;bt<4;bt++)
    hro[bt] = (size_t)(mb + b_wave + bt*16 + fr)*Hd + q*16;

  int4v acc1[4][4], acc2[4][4];
#pragma unroll
  for(int g=0;g<4;g++)
#pragma unroll
    for(int bt=0;bt<4;bt++){
      acc1[g][bt] = (int4v){0,0,0,0};
      acc2[g][bt] = (int4v){0,0,0,0};
    }

#pragma unroll 2
  for(int kc=0; kc<8; kc++){
    const int kb = kc*64;
    int4v wa[4], wb[4], hf[4], lf[4];
#pragma unroll
    for(int g=0;g<4;g++){
      wa[g] = *(const int4v*)&WA[wro[g] + kb];
      wb[g] = *(const int4v*)&WB[wro[g] + kb];
    }
#pragma unroll
    for(int bt=0;bt<4;bt++){
      hf[bt] = *(const int4v*)&hA[hro[bt] + kb];
      lf[bt] = *(const int4v*)&hB[hro[bt] + kb];
    }
#pragma unroll
    for(int g=0;g<4;g++)
#pragma unroll
      for(int bt=0;bt<4;bt++){
        acc1[g][bt] = __builtin_amdgcn_mfma_i32_16x16x64_i8(wa[g], hf[bt], acc1[g][bt], 0,0,0);
        acc2[g][bt] = __builtin_amdgcn_mfma_i32_16x16x64_i8(wa[g], lf[bt], acc2[g][bt], 0,0,0);
        acc2[g][bt] = __builtin_amdgcn_mfma_i32_16x16x64_i8(wb[g], hf[bt], acc2[g][bt], 0,0,0);
      }
  }

  // ---- epilogue
  const int j0 = jb + j_wave + q*4;
  float bsum[4][4];
#pragma unroll
  for(int g=0;g<4;g++){
    float4 a = *(const float4*)&bih[g*Hd + j0];
    float4 b = *(const float4*)&bhh[g*Hd + j0];
    bsum[g][0]=a.x+b.x; bsum[g][1]=a.y+b.y; bsum[g][2]=a.z+b.z; bsum[g][3]=a.w+b.w;
  }
#pragma unroll
  for(int bt=0;bt<4;bt++){
    const int b = mb + b_wave + bt*16 + fr;
    const size_t idx = (size_t)b*Hd + j0;
    float gv[4][4];
#pragma unroll
    for(int g=0;g<4;g++)
#pragma unroll
      for(int r=0;r<4;r++)
        gv[g][r] = fmaf(C1I, (float)acc1[g][bt][r],
                   fmaf(C2I, (float)acc2[g][bt][r], bsum[g][r]));
    {
      const float* grow = WihT + (size_t)xid[bt]*G4 + j0;
#pragma unroll
      for(int g=0;g<4;g++){
        float4 x = *(const float4*)&grow[g*Hd];
        gv[g][0]+=x.x; gv[g][1]+=x.y; gv[g][2]+=x.z; gv[g][3]+=x.w;
      }
    }
    float co[4];
    *(float4*)co = *(const float4*)&cin[idx];
    float cn[4];
    signed char a4[4], b4[4];
#pragma unroll
    for(int r=0;r<4;r++){
      const float I = sigm_f(gv[0][r]);
      const float F = sigm_f(gv[1][r]);
      const float G = tanh_f(gv[2][r]);
      const float O = sigm_f(gv[3][r]);
      cn[r] = F*co[r] + I*G;
      const float hn = O*tanh_f(cn[r]);
      i16split(hn, 32767.0f, a4[r], b4[r]);
    }
    *(float4*)&cout[idx] = *(float4*)cn;
    *(char4*)&hoA[idx] = *(char4*)a4;
    *(char4*)&hoB[idx] = *(char4*)b4;
  }
}

// ---------------------------------------------------------------------------
// Kernel B: logits STATS ONLY, BARRIER-FREE K-loop (direct VGPR fragments).
// 128x64 tile -> grid (64,8) = 512 blocks.  16 slabs of 32 cols.
// ---------------------------------------------------------------------------
__global__ __launch_bounds__(256, 2) void k_logits_i8(
    const signed char* __restrict__ hA, const signed char* __restrict__ hB,
    const signed char* __restrict__ WoA, const signed char* __restrict__ WoB,
    const float* __restrict__ bout,
    float* __restrict__ statM, float* __restrict__ statS, int* __restrict__ statI)
{
  const int tid = threadIdx.x;
  const int wave = tid >> 6, lane = tid & 63;
  const int mb = blockIdx.x * 128;
  const int vb = blockIdx.y * 64;
  const int m_wave = (wave & 1) * 64;
  const int n_wave = (wave >> 1) * 32;
  const int fr = lane & 15, q = lane >> 4;

  size_t mro[4], nro[2];
#pragma unroll
  for(int mt=0;mt<4;mt++)
    mro[mt] = (size_t)(mb + m_wave + mt*16 + fr)*Hd + q*16;
#pragma unroll
  for(int nt=0;nt<2;nt++)
    nro[nt] = (size_t)(vb + n_wave + nt*16 + fr)*Hd + q*16;

  int4v acc1[2][4], acc2[2][4];
#pragma unroll
  for(int nt=0;nt<2;nt++)
#pragma unroll
    for(int mt=0;mt<4;mt++){
      acc1[nt][mt] = (int4v){0,0,0,0};
      acc2[nt][mt] = (int4v){0,0,0,0};
    }

#pragma unroll 2
  for(int kc=0; kc<8; kc++){
    const int kb = kc*64;
    int4v ah[4], al[4], bh[2], bl[2];
#pragma unroll
    for(int mt=0;mt<4;mt++){
      ah[mt] = *(const int4v*)&hA[mro[mt] + kb];
      al[mt] = *(const int4v*)&hB[mro[mt] + kb];
    }
#pragma unroll
    for(int nt=0;nt<2;nt++){
      bh[nt] = *(const int4v*)&WoA[nro[nt] + kb];
      bl[nt] = *(const int4v*)&WoB[nro[nt] + kb];
    }
#pragma unroll
    for(int nt=0;nt<2;nt++)
#pragma unroll
      for(int mt=0;mt<4;mt++){
        acc1[nt][mt] = __builtin_amdgcn_mfma_i32_16x16x64_i8(ah[mt], bh[nt], acc1[nt][mt], 0,0,0);
        acc2[nt][mt] = __builtin_amdgcn_mfma_i32_16x16x64_i8(ah[mt], bl[nt], acc2[nt][mt], 0,0,0);
        acc2[nt][mt] = __builtin_amdgcn_mfma_i32_16x16x64_i8(al[mt], bh[nt], acc2[nt][mt], 0,0,0);
      }
  }

  const int slab = blockIdx.y*2 + (wave >> 1);
  float bo[2];
  int vv[2];
#pragma unroll
  for(int nt=0;nt<2;nt++){
    vv[nt] = vb + n_wave + nt*16 + fr;
    bo[nt] = bout[vv[nt]];
  }
#pragma unroll
  for(int mt=0;mt<4;mt++){
#pragma unroll
    for(int reg=0;reg<4;reg++){
      float lg[2];
#pragma unroll
      for(int nt=0;nt<2;nt++)
        lg[nt] = fmaf(C1I, (float)acc1[nt][mt][reg],
                 fmaf(C2I, (float)acc2[nt][mt][reg], bo[nt]));
      float vmax = lg[0];
      int   imax = vv[0];
      if(lg[1] > vmax || (lg[1] == vmax && vv[1] < imax)){ vmax = lg[1]; imax = vv[1]; }
#pragma unroll
      for(int off=1; off<16; off<<=1){
        const float vo = __shfl_xor(vmax, off);
        const int   io = __shfl_xor(imax, off);
        if(vo > vmax || (vo == vmax && io < imax)){ vmax = vo; imax = io; }
      }
      float s = __expf(lg[0] - vmax) + __expf(lg[1] - vmax);
#pragma unroll
      for(int off=1; off<16; off<<=1) s += __shfl_xor(s, off);
      if(fr == 0){
        const int m = mb + m_wave + mt*16 + q*4 + reg;
        statM[(size_t)slab*Bsz + m] = vmax;
        statS[(size_t)slab*Bsz + m] = s;
        statI[(size_t)slab*Bsz + m] = imax;
      }
    }
  }
}

// ---------------------------------------------------------------------------
// Kernel C (final step only): merge 16 slabs, write msg/masks/lp.
// ---------------------------------------------------------------------------
__global__ __launch_bounds__(256) void k_merge(
    const float* __restrict__ statM, const float* __restrict__ statS,
    const int* __restrict__ statI,
    float* __restrict__ msg, float* __restrict__ masks_out,
    float* __restrict__ lp_out, float* __restrict__ lpbuf,
    float* __restrict__ mbuf, int step)
{
  __shared__ int gI[32];
  const int tid = threadIdx.x;
  const int mb = blockIdx.x * 32;

  if(tid < 32){
    const int row = mb + tid;
    float gm = statM[row]; int gi = statI[row];
#pragma unroll
    for(int s=1;s<NSLAB;s++){
      const float m = statM[(size_t)s*Bsz + row];
      if(m > gm){ gm = m; gi = statI[(size_t)s*Bsz + row]; }
    }
    float tot = 0.0f;
#pragma unroll
    for(int s=0;s<NSLAB;s++)
      tot += statS[(size_t)s*Bsz + row] * __expf(statM[(size_t)s*Bsz + row] - gm);
    const float logp = -__logf(tot);
    const float mo  = mbuf[row];
    const float lpn = lpbuf[row] + logp * mo;
    masks_out[(size_t)step * Bsz + row] = mo;
    lp_out[row] = lpn;
    gI[tid] = gi;
  }
  __syncthreads();

  const int r  = tid >> 3;
  const int c8 = tid & 7;
  const int gi = gI[r];
  float* mrow = msg + ((size_t)step * Bsz + mb + r) * Vd;
#pragma unroll
  for(int i=0;i<16;i++){
    const int c = (i*8 + c8) * 4;
    float4 v;
    v.x = (c   == gi) ? 1.0f : 0.0f;
    v.y = (c+1 == gi) ? 1.0f : 0.0f;
    v.z = (c+2 == gi) ? 1.0f : 0.0f;
    v.w = (c+3 == gi) ? 1.0f : 0.0f;
    *(float4*)&mrow[c] = v;
  }
}

// ---------------------------------------------------------------------------
extern "C" void kernel_launch(void* const* d_in, const int* in_sizes, int n_in,
                              void* d_out, int out_size, void* d_ws, size_t ws_size,
                              hipStream_t stream) {
  const float* enc_h = (const float*)d_in[0];
  const float* enc_c = (const float*)d_in[1];
  const float* Wih   = (const float*)d_in[2];
  const float* Whh   = (const float*)d_in[3];
  const float* bih   = (const float*)d_in[4];
  const float* bhh   = (const float*)d_in[5];
  const float* Wout  = (const float*)d_in[6];
  const float* bout  = (const float*)d_in[7];

  float* out_msg   = (float*)d_out;                       // [16][8192][512]
  float* out_masks = out_msg + (size_t)Ld * Bsz * Vd;     // [16][1][8192]
  float* out_lp    = out_masks + (size_t)Ld * Bsz;        // [8192]

  char* ws = (char*)d_ws;
  float* WihT  = (float*)ws;          ws += (size_t)Vd * G4 * 4;           // 4 MB
  unsigned short* WhhHi = (unsigned short*)ws; ws += (size_t)G4 * Hd * 2;  // 2 MB
  unsigned short* WhhLo = (unsigned short*)ws; ws += (size_t)G4 * Hd * 2;  // 2 MB
  unsigned short* encHi = (unsigned short*)ws; ws += (size_t)Bsz * Hd * 2; // 8 MB
  unsigned short* encLo = (unsigned short*)ws; ws += (size_t)Bsz * Hd * 2; // 8 MB
  signed char* WhhA = (signed char*)ws; ws += (size_t)G4 * Hd;             // 1 MB
  signed char* WhhB = (signed char*)ws; ws += (size_t)G4 * Hd;             // 1 MB
  signed char* WoA  = (signed char*)ws; ws += (size_t)Vd * Hd;             // 256 KB
  signed char* WoB  = (signed char*)ws; ws += (size_t)Vd * Hd;             // 256 KB
  signed char* ha0  = (signed char*)ws; ws += (size_t)Bsz * Hd;            // 4 MB
  signed char* hb0  = (signed char*)ws; ws += (size_t)Bsz * Hd;
  signed char* ha1  = (signed char*)ws; ws += (size_t)Bsz * Hd;
  signed char* hb1  = (signed char*)ws; ws += (size_t)Bsz * Hd;
  float* cbuf   = (float*)ws;  ws += (size_t)Bsz * Hd * 4;                 // 16 MB
  float* statM  = (float*)ws;  ws += (size_t)NSLAB * Bsz * 4;              // 512 KB
  float* statS  = (float*)ws;  ws += (size_t)NSLAB * Bsz * 4;
  int*   statI  = (int*)ws;    ws += (size_t)NSLAB * Bsz * 4;
  float* lpbuf  = (float*)ws;  ws += (size_t)Bsz * 4;
  float* mbuf   = (float*)ws;  ws += (size_t)Bsz * 4;

  k_transpose<<<dim3(Vd/32, G4/32), dim3(32,8), 0, stream>>>(Wih, WihT);
  k_split<<<(G4*Hd+255)/256, 256, 0, stream>>>(Whh, WhhHi, WhhLo, G4*Hd);
  k_split<<<(Bsz*Hd+255)/256, 256, 0, stream>>>(enc_h, encHi, encLo, Bsz*Hd);
  k_split_i8<<<(G4*Hd+255)/256, 256, 0, stream>>>(Whh, WhhA, WhhB, 524288.0f, G4*Hd);
  k_split_i8<<<(Vd*Hd+255)/256, 256, 0, stream>>>(Wout, WoA, WoB, 524288.0f, Vd*Hd);

  for(int t=0; t<Ld; t++){
    signed char* haOut = (t & 1) ? ha1 : ha0;
    signed char* hbOut = (t & 1) ? hb1 : hb0;
    const signed char* haIn = (t & 1) ? ha0 : ha1;
    const signed char* hbIn = (t & 1) ? hb0 : hb1;

    if(t == 0){
      k_lstm_bf16<<<dim3(Bsz/128, Hd/32), 256, 0, stream>>>(
          encHi, encLo, enc_c, haOut, hbOut, cbuf, WhhHi, WhhLo, bih, bhh);
    } else {
      k_lstm_i8<<<dim3(Bsz/128, Hd/32), 256, 0, stream>>>(
          haIn, hbIn, cbuf, haOut, hbOut, cbuf, WhhA, WhhB, WihT, bih, bhh,
          statM, statS, statI, out_msg, out_masks, out_lp, lpbuf, mbuf, t-1);
    }
    k_logits_i8<<<dim3(Bsz/128, Vd/64), 256, 0, stream>>>(
        haOut, hbOut, WoA, WoB, bout, statM, statS, statI);
  }
  k_merge<<<Bsz/32, 256, 0, stream>>>(statM, statS, statI,
                                      out_msg, out_masks, out_lp,
                                      lpbuf, mbuf, Ld-1);
}

// Round 11
// 1248.126 us; speedup vs baseline: 1.5766x; 1.5766x over previous
//
#include <hip/hip_runtime.h>
#include <math.h>

#define Bsz 8192
#define Hd  512
#define Vd  512
#define Ld  16
#define G4  2048   // 4*Hd
#define NSLAB 16   // 32-col vocab slabs

using short8 = __attribute__((ext_vector_type(8))) short;
using f32x4  = __attribute__((ext_vector_type(4))) float;
using int4v  = __attribute__((ext_vector_type(4))) int;

__device__ __forceinline__ float sigm_f(float x){
  return __builtin_amdgcn_rcpf(1.0f + __expf(-x));
}
__device__ __forceinline__ float tanh_f(float x){
  return 1.0f - 2.0f * __builtin_amdgcn_rcpf(1.0f + __expf(2.0f * x));
}

// bf16 bit helpers (RNE)
__device__ __forceinline__ unsigned short f2bf(float f){
  unsigned int u = __float_as_uint(f);
  u = (u + 0x7fffu + ((u >> 16) & 1u)) >> 16;
  return (unsigned short)u;
}
__device__ __forceinline__ float bf2f(unsigned short b){
  return __uint_as_float(((unsigned int)b) << 16);
}

// int16 -> signed i8 pair: q = 256*a + b, a,b in [-128,127]
__device__ __forceinline__ void i16split(float x, float S, signed char& a, signed char& b){
  int q = (int)rintf(x * S);
  q = min(max(q, -32640), 32639);
  const int ah = (q + 128) >> 8;
  a = (signed char)ah;
  b = (signed char)(q - (ah << 8));
}

__device__ __forceinline__ void gl_lds16(const void* g, void* l){
  __builtin_amdgcn_global_load_lds((const __attribute__((address_space(1))) void*)g,
                                   (__attribute__((address_space(3))) void*)l, 16, 0, 0);
}

// reconstruction constants: value = (65536*acc1 + 256*acc2) / (2^19 * 32767)
#define C1I (65536.0f / (524288.0f * 32767.0f))
#define C2I (  256.0f / (524288.0f * 32767.0f))

// ---------------------------------------------------------------------------
// Transpose W_ih (2048 x 512) -> W_ihT (512 x 2048): one-hot gather rows.
// ---------------------------------------------------------------------------
__global__ __launch_bounds__(256) void k_transpose(const float* __restrict__ in,
                                                   float* __restrict__ out){
  __shared__ float tile[32][33];
  const int tx = threadIdx.x, ty = threadIdx.y;
  const int v0 = blockIdx.x * 32, n0 = blockIdx.y * 32;
#pragma unroll
  for(int i=0;i<4;i++)
    tile[ty+i*8][tx] = in[(size_t)(n0+ty+i*8)*Vd + v0+tx];
  __syncthreads();
#pragma unroll
  for(int i=0;i<4;i++)
    out[(size_t)(v0+ty+i*8)*G4 + n0+tx] = tile[tx][ty+i*8];
}

// ---------------------------------------------------------------------------
// Fused precompute: one kernel does all splits.
//   [0, 1M)        : Whh -> bf16 hi/lo AND i8 planes (reads Whh once)
//   [1M, 1.25M)    : Wout -> i8 planes
//   [1.25M, 5.25M) : enc_h -> bf16 hi/lo
// ---------------------------------------------------------------------------
__global__ __launch_bounds__(256) void k_prep(
    const float* __restrict__ Whh, const float* __restrict__ Wout,
    const float* __restrict__ enc_h,
    unsigned short* __restrict__ WhhHi, unsigned short* __restrict__ WhhLo,
    signed char* __restrict__ WhhA, signed char* __restrict__ WhhB,
    signed char* __restrict__ WoA, signed char* __restrict__ WoB,
    unsigned short* __restrict__ encHi, unsigned short* __restrict__ encLo)
{
  const int i = blockIdx.x*256 + threadIdx.x;
  const int NW = G4*Hd;            // 1M
  const int NO = Vd*Hd;            // 256K
  const int NE = Bsz*Hd;           // 4M
  if(i < NW){
    const float x = Whh[i];
    const unsigned short h = f2bf(x);
    WhhHi[i] = h;
    WhhLo[i] = f2bf(x - bf2f(h));
    signed char a, b;
    i16split(x, 524288.0f, a, b);
    WhhA[i] = a; WhhB[i] = b;
  } else if(i < NW + NO){
    const int k = i - NW;
    signed char a, b;
    i16split(Wout[k], 524288.0f, a, b);
    WoA[k] = a; WoB[k] = b;
  } else if(i < NW + NO + NE){
    const int k = i - NW - NO;
    const float x = enc_h[k];
    const unsigned short h = f2bf(x);
    encHi[k] = h;
    encLo[k] = f2bf(x - bf2f(h));
  }
}

// ---------------------------------------------------------------------------
// Kernel A0 (step 0 only): bf16x2 3-product MFMA LSTM step from enc_h.
// ---------------------------------------------------------------------------
__global__ __launch_bounds__(256, 2) void k_lstm_bf16(
    const unsigned short* __restrict__ hh, const unsigned short* __restrict__ hl,
    const float* __restrict__ cin,
    signed char* __restrict__ ha, signed char* __restrict__ hb,
    float* __restrict__ cout,
    const unsigned short* __restrict__ Whh_hi, const unsigned short* __restrict__ Whh_lo,
    const float* __restrict__ bih, const float* __restrict__ bhh)
{
  __shared__ unsigned short lds[2][16384];
  const int tid = threadIdx.x;
  const int wave = tid >> 6, lane = tid & 63;
  const int mb = blockIdx.x * 128;
  const int jb = blockIdx.y * 32;
  const int b_wave = (wave & 1) * 64;
  const int j_wave = (wave >> 1) * 16;
  const int fr = lane & 15, q = lane >> 4;
  const int lr = lane >> 2, jj = lane & 3;

  auto stage = [&](int k0, int bsel){
    unsigned short* Whi = lds[bsel];
    unsigned short* Wlo = lds[bsel] + 4096;
    unsigned short* Hhi = lds[bsel] + 8192;
    unsigned short* Hlo = lds[bsel] + 12288;
#pragma unroll
    for(int p=0;p<2;p++){
      const int s = wave*2 + p;
      const int r = s*16 + lr;
      const int j = jj ^ ((r >> 1) & 3);
      const size_t ka = (size_t)k0 + j*8;
      const size_t wrow = (size_t)((r >> 5)*Hd + jb + (r & 31));
      gl_lds16(Whh_hi + wrow*Hd + ka, &Whi[s*512]);
      gl_lds16(Whh_lo + wrow*Hd + ka, &Wlo[s*512]);
      gl_lds16(hh + (size_t)(mb + r)*Hd + ka, &Hhi[s*512]);
      gl_lds16(hl + (size_t)(mb + r)*Hd + ka, &Hlo[s*512]);
    }
  };

  stage(0, 0);

  const int j0 = jb + j_wave + q*4;
  float bsum[4][4];
#pragma unroll
  for(int g=0;g<4;g++){
    float4 a = *(const float4*)&bih[g*Hd + j0];
    float4 b = *(const float4*)&bhh[g*Hd + j0];
    bsum[g][0]=a.x+b.x; bsum[g][1]=a.y+b.y; bsum[g][2]=a.z+b.z; bsum[g][3]=a.w+b.w;
  }

  f32x4 acc[4][4];
#pragma unroll
  for(int g=0;g<4;g++)
#pragma unroll
    for(int bt=0;bt<4;bt++) acc[g][bt] = (f32x4){0.f,0.f,0.f,0.f};

  for(int kc=0; kc<16; kc++){
    __syncthreads();
    if(kc < 15) stage((kc+1)*32, (kc+1)&1);

    const unsigned short* Whi = lds[kc&1];
    const unsigned short* Wlo = lds[kc&1] + 4096;
    const unsigned short* Hhi = lds[kc&1] + 8192;
    const unsigned short* Hlo = lds[kc&1] + 12288;

    short8 wh[4], wl[4], hf[4], lf[4];
#pragma unroll
    for(int g=0;g<4;g++){
      const int r = g*32 + j_wave + fr;
      const int off = r*32 + ((q ^ ((r >> 1) & 3)) << 3);
      wh[g] = *(const short8*)&Whi[off];
      wl[g] = *(const short8*)&Wlo[off];
    }
#pragma unroll
    for(int bt=0;bt<4;bt++){
      const int r = b_wave + bt*16 + fr;
      const int off = r*32 + ((q ^ ((r >> 1) & 3)) << 3);
      hf[bt] = *(const short8*)&Hhi[off];
      lf[bt] = *(const short8*)&Hlo[off];
    }
#pragma unroll
    for(int g=0;g<4;g++)
#pragma unroll
      for(int bt=0;bt<4;bt++){
        acc[g][bt] = __builtin_amdgcn_mfma_f32_16x16x32_bf16(wh[g], hf[bt], acc[g][bt], 0,0,0);
        acc[g][bt] = __builtin_amdgcn_mfma_f32_16x16x32_bf16(wh[g], lf[bt], acc[g][bt], 0,0,0);
        acc[g][bt] = __builtin_amdgcn_mfma_f32_16x16x32_bf16(wl[g], hf[bt], acc[g][bt], 0,0,0);
      }
  }

#pragma unroll
  for(int bt=0;bt<4;bt++){
    const int b = mb + b_wave + bt*16 + fr;
    const size_t idx = (size_t)b*Hd + j0;
    float gv[4][4];
#pragma unroll
    for(int g=0;g<4;g++)
#pragma unroll
      for(int r=0;r<4;r++) gv[g][r] = acc[g][bt][r] + bsum[g][r];
    float co[4];
    *(float4*)co = *(const float4*)&cin[idx];
    float cn[4];
    signed char a4[4], b4[4];
#pragma unroll
    for(int r=0;r<4;r++){
      const float I = sigm_f(gv[0][r]);
      const float F = sigm_f(gv[1][r]);
      const float G = tanh_f(gv[2][r]);
      const float O = sigm_f(gv[3][r]);
      cn[r] = F*co[r] + I*G;
      const float hn = O*tanh_f(cn[r]);
      i16split(hn, 32767.0f, a4[r], b4[r]);
    }
    *(float4*)&cout[idx] = *(float4*)cn;
    *(char4*)&ha[idx] = *(char4*)a4;
    *(char4*)&hb[idx] = *(char4*)b4;
  }
}

// ---------------------------------------------------------------------------
// Kernel A (steps >=1): i8 LSTM step with fused prev-step merge (r9 struct).
// Stats layout [row][slab]: prologue reads 64 contiguous bytes per thread.
// ---------------------------------------------------------------------------
__global__ __launch_bounds__(256, 2) void k_lstm_i8(
    const signed char* __restrict__ hA, const signed char* __restrict__ hB,
    const float* __restrict__ cin,
    signed char* __restrict__ hoA, signed char* __restrict__ hoB,
    float* __restrict__ cout,
    const signed char* __restrict__ WA, const signed char* __restrict__ WB,
    const float* __restrict__ WihT, const float* __restrict__ bih,
    const float* __restrict__ bhh,
    const float* __restrict__ statM, const float* __restrict__ statS,
    const int* __restrict__ statI,
    float* __restrict__ msg, float* __restrict__ masks_out,
    float* __restrict__ lp_out, float* __restrict__ lpbuf,
    float* __restrict__ mbuf, int prev)
{
  __shared__ unsigned char lds[2][32768];
  __shared__ int gIs[128];
  const int tid = threadIdx.x;
  const int wave = tid >> 6, lane = tid & 63;
  const int mb = blockIdx.x * 128;
  const int jb = blockIdx.y * 32;
  const int b_wave = (wave & 1) * 64;
  const int j_wave = (wave >> 1) * 16;
  const int fr = lane & 15, q = lane >> 4;
  const int lr = lane >> 2, jj = lane & 3;

  auto stage = [&](int k0, int bsel){
    unsigned char* Wa = lds[bsel];
    unsigned char* Wb = lds[bsel] + 8192;
    unsigned char* Ha = lds[bsel] + 16384;
    unsigned char* Hb = lds[bsel] + 24576;
#pragma unroll
    for(int p=0;p<2;p++){
      const int s = wave*2 + p;
      const int r = s*16 + lr;
      const int j = jj ^ ((r >> 1) & 3);
      const size_t ka = (size_t)k0 + j*16;
      const size_t wrow = (size_t)((r >> 5)*Hd + jb + (r & 31));
      gl_lds16(WA + wrow*Hd + ka, &Wa[s*1024]);
      gl_lds16(WB + wrow*Hd + ka, &Wb[s*1024]);
      gl_lds16(hA + (size_t)(mb + r)*Hd + ka, &Ha[s*1024]);
      gl_lds16(hB + (size_t)(mb + r)*Hd + ka, &Hb[s*1024]);
    }
  };

  stage(0, 0);   // async staging in flight during merge prologue

  // ---- merge prologue: prev-step stats -> gi per row (+ scalar outputs)
  if(tid < 128){
    const int row = mb + tid;
    const float* rM = statM + (size_t)row*NSLAB;
    const int*   rI = statI + (size_t)row*NSLAB;
    float gm = rM[0]; int gi = rI[0];
#pragma unroll
    for(int s=1;s<NSLAB;s++){
      const float m = rM[s];
      if(m > gm){ gm = m; gi = rI[s]; }
    }
    if(blockIdx.y == 0){
      const float* rS = statS + (size_t)row*NSLAB;
      float tot = 0.0f;
#pragma unroll
      for(int s=0;s<NSLAB;s++)
        tot += rS[s] * __expf(rM[s] - gm);
      const float logp = -__logf(tot);
      const float mo  = (prev == 0) ? 1.0f : mbuf[row];
      const float lpo = (prev == 0) ? 0.0f : lpbuf[row];
      const float lpn = lpo + logp * mo;
      masks_out[(size_t)prev * Bsz + row] = mo;
      lp_out[row] = lpn;
      lpbuf[row]  = lpn;
      mbuf[row]   = mo * ((gi == Vd-1) ? 0.0f : 1.0f);
    }
    gIs[tid] = gi;
  }
  __syncthreads();

  // one-hot msg slice: this block writes cols [jb, jb+32) of prev-step msg
  {
    const int r  = tid >> 1;
    const int c0 = jb + (tid & 1) * 16;
    const int gi = gIs[r];
    float* mrow = msg + ((size_t)prev * Bsz + mb + r) * Vd;
#pragma unroll
    for(int i=0;i<4;i++){
      const int c = c0 + i*4;
      float4 v;
      v.x = (c   == gi) ? 1.0f : 0.0f;
      v.y = (c+1 == gi) ? 1.0f : 0.0f;
      v.z = (c+2 == gi) ? 1.0f : 0.0f;
      v.w = (c+3 == gi) ? 1.0f : 0.0f;
      *(float4*)&mrow[c] = v;
    }
  }

  int xid[4];
#pragma unroll
  for(int bt=0;bt<4;bt++)
    xid[bt] = gIs[b_wave + bt*16 + fr];

  int4v acc1[4][4], acc2[4][4];
#pragma unroll
  for(int g=0;g<4;g++)
#pragma unroll
    for(int bt=0;bt<4;bt++){
      acc1[g][bt] = (int4v){0,0,0,0};
      acc2[g][bt] = (int4v){0,0,0,0};
    }

  for(int kc=0; kc<8; kc++){
    __syncthreads();
    if(kc < 7) stage((kc+1)*64, (kc+1)&1);

    const unsigned char* Wa = lds[kc&1];
    const unsigned char* Wb = lds[kc&1] + 8192;
    const unsigned char* Ha = lds[kc&1] + 16384;
    const unsigned char* Hb = lds[kc&1] + 24576;

    int4v wa[4], wb[4], hf[4], lf[4];
#pragma unroll
    for(int g=0;g<4;g++){
      const int r = g*32 + j_wave + fr;
      const int off = r*64 + ((q ^ ((r >> 1) & 3)) << 4);
      wa[g] = *(const int4v*)&Wa[off];
      wb[g] = *(const int4v*)&Wb[off];
    }
#pragma unroll
    for(int bt=0;bt<4;bt++){
      const int r = b_wave + bt*16 + fr;
      const int off = r*64 + ((q ^ ((r >> 1) & 3)) << 4);
      hf[bt] = *(const int4v*)&Ha[off];
      lf[bt] = *(const int4v*)&Hb[off];
    }
#pragma unroll
    for(int g=0;g<4;g++)
#pragma unroll
      for(int bt=0;bt<4;bt++){
        acc1[g][bt] = __builtin_amdgcn_mfma_i32_16x16x64_i8(wa[g], hf[bt], acc1[g][bt], 0,0,0);
        acc2[g][bt] = __builtin_amdgcn_mfma_i32_16x16x64_i8(wa[g], lf[bt], acc2[g][bt], 0,0,0);
        acc2[g][bt] = __builtin_amdgcn_mfma_i32_16x16x64_i8(wb[g], hf[bt], acc2[g][bt], 0,0,0);
      }
  }

  const int j0 = jb + j_wave + q*4;
  float bsum[4][4];
#pragma unroll
  for(int g=0;g<4;g++){
    float4 a = *(const float4*)&bih[g*Hd + j0];
    float4 b = *(const float4*)&bhh[g*Hd + j0];
    bsum[g][0]=a.x+b.x; bsum[g][1]=a.y+b.y; bsum[g][2]=a.z+b.z; bsum[g][3]=a.w+b.w;
  }
#pragma unroll
  for(int bt=0;bt<4;bt++){
    const int b = mb + b_wave + bt*16 + fr;
    const size_t idx = (size_t)b*Hd + j0;
    float gv[4][4];
#pragma unroll
    for(int g=0;g<4;g++)
#pragma unroll
      for(int r=0;r<4;r++)
        gv[g][r] = fmaf(C1I, (float)acc1[g][bt][r],
                   fmaf(C2I, (float)acc2[g][bt][r], bsum[g][r]));
    {
      const float* grow = WihT + (size_t)xid[bt]*G4 + j0;
#pragma unroll
      for(int g=0;g<4;g++){
        float4 x = *(const float4*)&grow[g*Hd];
        gv[g][0]+=x.x; gv[g][1]+=x.y; gv[g][2]+=x.z; gv[g][3]+=x.w;
      }
    }
    float co[4];
    *(float4*)co = *(const float4*)&cin[idx];
    float cn[4];
    signed char a4[4], b4[4];
#pragma unroll
    for(int r=0;r<4;r++){
      const float I = sigm_f(gv[0][r]);
      const float F = sigm_f(gv[1][r]);
      const float G = tanh_f(gv[2][r]);
      const float O = sigm_f(gv[3][r]);
      cn[r] = F*co[r] + I*G;
      const float hn = O*tanh_f(cn[r]);
      i16split(hn, 32767.0f, a4[r], b4[r]);
    }
    *(float4*)&cout[idx] = *(float4*)cn;
    *(char4*)&hoA[idx] = *(char4*)a4;
    *(char4*)&hoB[idx] = *(char4*)b4;
  }
}

// ---------------------------------------------------------------------------
// Kernel B: logits STATS ONLY (r9 structure).  128x64 tile, grid (64,8),
// dbuf LDS.  Stats written [row][slab].
// ---------------------------------------------------------------------------
__global__ __launch_bounds__(256, 2) void k_logits_i8(
    const signed char* __restrict__ hA, const signed char* __restrict__ hB,
    const signed char* __restrict__ WoA, const signed char* __restrict__ WoB,
    const float* __restrict__ bout,
    float* __restrict__ statM, float* __restrict__ statS, int* __restrict__ statI)
{
  __shared__ unsigned char lds[2][24576];   // Ha 8K | Hb 8K | Wa 4K | Wb 4K
  const int tid = threadIdx.x;
  const int wave = tid >> 6, lane = tid & 63;
  const int mb = blockIdx.x * 128;
  const int vb = blockIdx.y * 64;
  const int m_wave = (wave & 1) * 64;
  const int n_wave = (wave >> 1) * 32;
  const int fr = lane & 15, q = lane >> 4;
  const int lr = lane >> 2, jj = lane & 3;

  auto stage = [&](int k0, int bsel){
    unsigned char* Ha = lds[bsel];
    unsigned char* Hb = lds[bsel] + 8192;
    unsigned char* Wa = lds[bsel] + 16384;
    unsigned char* Wb = lds[bsel] + 20480;
#pragma unroll
    for(int p=0;p<2;p++){
      const int s = wave*2 + p;
      const int r = s*16 + lr;
      const int j = jj ^ ((r >> 1) & 3);
      const size_t ka = (size_t)k0 + j*16;
      gl_lds16(hA + (size_t)(mb + r)*Hd + ka, &Ha[s*1024]);
      gl_lds16(hB + (size_t)(mb + r)*Hd + ka, &Hb[s*1024]);
    }
    {
      const int r = wave*16 + lr;
      const int j = jj ^ ((r >> 1) & 3);
      const size_t ka = (size_t)k0 + j*16;
      gl_lds16(WoA + (size_t)(vb + r)*Hd + ka, &Wa[wave*1024]);
      gl_lds16(WoB + (size_t)(vb + r)*Hd + ka, &Wb[wave*1024]);
    }
  };

  stage(0, 0);

  int4v acc1[2][4], acc2[2][4];
#pragma unroll
  for(int nt=0;nt<2;nt++)
#pragma unroll
    for(int mt=0;mt<4;mt++){
      acc1[nt][mt] = (int4v){0,0,0,0};
      acc2[nt][mt] = (int4v){0,0,0,0};
    }

  for(int kc=0; kc<8; kc++){
    __syncthreads();
    if(kc < 7) stage((kc+1)*64, (kc+1)&1);

    const unsigned char* Ha = lds[kc&1];
    const unsigned char* Hb = lds[kc&1] + 8192;
    const unsigned char* Wa = lds[kc&1] + 16384;
    const unsigned char* Wb = lds[kc&1] + 20480;

    int4v ah[4], al[4], bh[2], bl[2];
#pragma unroll
    for(int mt=0;mt<4;mt++){
      const int r = m_wave + mt*16 + fr;
      const int off = r*64 + ((q ^ ((r >> 1) & 3)) << 4);
      ah[mt] = *(const int4v*)&Ha[off];
      al[mt] = *(const int4v*)&Hb[off];
    }
#pragma unroll
    for(int nt=0;nt<2;nt++){
      const int r = n_wave + nt*16 + fr;
      const int off = r*64 + ((q ^ ((r >> 1) & 3)) << 4);
      bh[nt] = *(const int4v*)&Wa[off];
      bl[nt] = *(const int4v*)&Wb[off];
    }
#pragma unroll
    for(int nt=0;nt<2;nt++)
#pragma unroll
      for(int mt=0;mt<4;mt++){
        acc1[nt][mt] = __builtin_amdgcn_mfma_i32_16x16x64_i8(ah[mt], bh[nt], acc1[nt][mt], 0,0,0);
        acc2[nt][mt] = __builtin_amdgcn_mfma_i32_16x16x64_i8(ah[mt], bl[nt], acc2[nt][mt], 0,0,0);
        acc2[nt][mt] = __builtin_amdgcn_mfma_i32_16x16x64_i8(al[mt], bh[nt], acc2[nt][mt], 0,0,0);
      }
  }

  const int slab = blockIdx.y*2 + (wave >> 1);
  float bo[2];
  int vv[2];
#pragma unroll
  for(int nt=0;nt<2;nt++){
    vv[nt] = vb + n_wave + nt*16 + fr;
    bo[nt] = bout[vv[nt]];
  }
#pragma unroll
  for(int mt=0;mt<4;mt++){
#pragma unroll
    for(int reg=0;reg<4;reg++){
      float lg[2];
#pragma unroll
      for(int nt=0;nt<2;nt++)
        lg[nt] = fmaf(C1I, (float)acc1[nt][mt][reg],
                 fmaf(C2I, (float)acc2[nt][mt][reg], bo[nt]));
      float vmax = lg[0];
      int   imax = vv[0];
      if(lg[1] > vmax || (lg[1] == vmax && vv[1] < imax)){ vmax = lg[1]; imax = vv[1]; }
#pragma unroll
      for(int off=1; off<16; off<<=1){
        const float vo = __shfl_xor(vmax, off);
        const int   io = __shfl_xor(imax, off);
        if(vo > vmax || (vo == vmax && io < imax)){ vmax = vo; imax = io; }
      }
      float s = __expf(lg[0] - vmax) + __expf(lg[1] - vmax);
#pragma unroll
      for(int off=1; off<16; off<<=1) s += __shfl_xor(s, off);
      if(fr == 0){
        const int m = mb + m_wave + mt*16 + q*4 + reg;
        statM[(size_t)m*NSLAB + slab] = vmax;
        statS[(size_t)m*NSLAB + slab] = s;
        statI[(size_t)m*NSLAB + slab] = imax;
      }
    }
  }
}

// ---------------------------------------------------------------------------
// Kernel C (final step only): merge 16 slabs, write msg/masks/lp.
// ---------------------------------------------------------------------------
__global__ __launch_bounds__(256) void k_merge(
    const float* __restrict__ statM, const float* __restrict__ statS,
    const int* __restrict__ statI,
    float* __restrict__ msg, float* __restrict__ masks_out,
    float* __restrict__ lp_out, float* __restrict__ lpbuf,
    float* __restrict__ mbuf, int step)
{
  __shared__ int gI[32];
  const int tid = threadIdx.x;
  const int mb = blockIdx.x * 32;

  if(tid < 32){
    const int row = mb + tid;
    const float* rM = statM + (size_t)row*NSLAB;
    const float* rS = statS + (size_t)row*NSLAB;
    const int*   rI = statI + (size_t)row*NSLAB;
    float gm = rM[0]; int gi = rI[0];
#pragma unroll
    for(int s=1;s<NSLAB;s++){
      const float m = rM[s];
      if(m > gm){ gm = m; gi = rI[s]; }
    }
    float tot = 0.0f;
#pragma unroll
    for(int s=0;s<NSLAB;s++)
      tot += rS[s] * __expf(rM[s] - gm);
    const float logp = -__logf(tot);
    const float mo  = mbuf[row];
    const float lpn = lpbuf[row] + logp * mo;
    masks_out[(size_t)step * Bsz + row] = mo;
    lp_out[row] = lpn;
    gI[tid] = gi;
  }
  __syncthreads();

  const int r  = tid >> 3;
  const int c8 = tid & 7;
  const int gi = gI[r];
  float* mrow = msg + ((size_t)step * Bsz + mb + r) * Vd;
#pragma unroll
  for(int i=0;i<16;i++){
    const int c = (i*8 + c8) * 4;
    float4 v;
    v.x = (c   == gi) ? 1.0f : 0.0f;
    v.y = (c+1 == gi) ? 1.0f : 0.0f;
    v.z = (c+2 == gi) ? 1.0f : 0.0f;
    v.w = (c+3 == gi) ? 1.0f : 0.0f;
    *(float4*)&mrow[c] = v;
  }
}

// ---------------------------------------------------------------------------
extern "C" void kernel_launch(void* const* d_in, const int* in_sizes, int n_in,
                              void* d_out, int out_size, void* d_ws, size_t ws_size,
                              hipStream_t stream) {
  const float* enc_h = (const float*)d_in[0];
  const float* enc_c = (const float*)d_in[1];
  const float* Wih   = (const float*)d_in[2];
  const float* Whh   = (const float*)d_in[3];
  const float* bih   = (const float*)d_in[4];
  const float* bhh   = (const float*)d_in[5];
  const float* Wout  = (const float*)d_in[6];
  const float* bout  = (const float*)d_in[7];

  float* out_msg   = (float*)d_out;                       // [16][8192][512]
  float* out_masks = out_msg + (size_t)Ld * Bsz * Vd;     // [16][1][8192]
  float* out_lp    = out_masks + (size_t)Ld * Bsz;        // [8192]

  char* ws = (char*)d_ws;
  float* WihT  = (float*)ws;          ws += (size_t)Vd * G4 * 4;           // 4 MB
  unsigned short* WhhHi = (unsigned short*)ws; ws += (size_t)G4 * Hd * 2;  // 2 MB
  unsigned short* WhhLo = (unsigned short*)ws; ws += (size_t)G4 * Hd * 2;  // 2 MB
  unsigned short* encHi = (unsigned short*)ws; ws += (size_t)Bsz * Hd * 2; // 8 MB
  unsigned short* encLo = (unsigned short*)ws; ws += (size_t)Bsz * Hd * 2; // 8 MB
  signed char* WhhA = (signed char*)ws; ws += (size_t)G4 * Hd;             // 1 MB
  signed char* WhhB = (signed char*)ws; ws += (size_t)G4 * Hd;             // 1 MB
  signed char* WoA  = (signed char*)ws; ws += (size_t)Vd * Hd;             // 256 KB
  signed char* WoB  = (signed char*)ws; ws += (size_t)Vd * Hd;             // 256 KB
  signed char* ha0  = (signed char*)ws; ws += (size_t)Bsz * Hd;            // 4 MB
  signed char* hb0  = (signed char*)ws; ws += (size_t)Bsz * Hd;
  signed char* ha1  = (signed char*)ws; ws += (size_t)Bsz * Hd;
  signed char* hb1  = (signed char*)ws; ws += (size_t)Bsz * Hd;
  float* cbuf   = (float*)ws;  ws += (size_t)Bsz * Hd * 4;                 // 16 MB
  float* statM  = (float*)ws;  ws += (size_t)NSLAB * Bsz * 4;              // 512 KB
  float* statS  = (float*)ws;  ws += (size_t)NSLAB * Bsz * 4;
  int*   statI  = (int*)ws;    ws += (size_t)NSLAB * Bsz * 4;
  float* lpbuf  = (float*)ws;  ws += (size_t)Bsz * 4;
  float* mbuf   = (float*)ws;  ws += (size_t)Bsz * 4;

  k_transpose<<<dim3(Vd/32, G4/32), dim3(32,8), 0, stream>>>(Wih, WihT);
  {
    const int ntot = G4*Hd + Vd*Hd + Bsz*Hd;
    k_prep<<<(ntot+255)/256, 256, 0, stream>>>(Whh, Wout, enc_h,
        WhhHi, WhhLo, WhhA, WhhB, WoA, WoB, encHi, encLo);
  }

  for(int t=0; t<Ld; t++){
    signed char* haOut = (t & 1) ? ha1 : ha0;
    signed char* hbOut = (t & 1) ? hb1 : hb0;
    const signed char* haIn = (t & 1) ? ha0 : ha1;
    const signed char* hbIn = (t & 1) ? hb0 : hb1;

    if(t == 0){
      k_lstm_bf16<<<dim3(Bsz/128, Hd/32), 256, 0, stream>>>(
          encHi, encLo, enc_c, haOut, hbOut, cbuf, WhhHi, WhhLo, bih, bhh);
    } else {
      k_lstm_i8<<<dim3(Bsz/128, Hd/32), 256, 0, stream>>>(
          haIn, hbIn, cbuf, haOut, hbOut, cbuf, WhhA, WhhB, WihT, bih, bhh,
          statM, statS, statI, out_msg, out_masks, out_lp, lpbuf, mbuf, t-1);
    }
    k_logits_i8<<<dim3(Bsz/128, Vd/64), 256, 0, stream>>>(
        haOut, hbOut, WoA, WoB, bout, statM, statS, statI);
  }
  k_merge<<<Bsz/32, 256, 0, stream>>>(statM, statS, statI,
                                      out_msg, out_masks, out_lp,
                                      lpbuf, mbuf, Ld-1);
}

// Round 12
// 1188.854 us; speedup vs baseline: 1.6552x; 1.0499x over previous
//
#include <hip/hip_runtime.h>
#include <math.h>

#define Bsz 8192
#define Hd  512
#define Vd  512
#define Ld  16
#define G4  2048   // 4*Hd
#define NSLAB 16   // 32-col vocab slabs

using short8 = __attribute__((ext_vector_type(8))) short;
using f32x4  = __attribute__((ext_vector_type(4))) float;
using int4v  = __attribute__((ext_vector_type(4))) int;

__device__ __forceinline__ float sigm_f(float x){
  return __builtin_amdgcn_rcpf(1.0f + __expf(-x));
}
__device__ __forceinline__ float tanh_f(float x){
  return 1.0f - 2.0f * __builtin_amdgcn_rcpf(1.0f + __expf(2.0f * x));
}

// int16 -> signed i8 pair: q = 256*a + b, a,b in [-128,127]
__device__ __forceinline__ void i16split(float x, float S, signed char& a, signed char& b){
  int q = (int)rintf(x * S);
  q = min(max(q, -32640), 32639);
  const int ah = (q + 128) >> 8;
  a = (signed char)ah;
  b = (signed char)(q - (ah << 8));
}

__device__ __forceinline__ void gl_lds16(const void* g, void* l){
  __builtin_amdgcn_global_load_lds((const __attribute__((address_space(1))) void*)g,
                                   (__attribute__((address_space(3))) void*)l, 16, 0, 0);
}

// reconstruction: value = (65536*acc1 + 256*acc2) / (Sw * Sh)
#define C1I (65536.0f / (524288.0f * 32767.0f))   // steps >=1 (Sh=32767)
#define C2I (  256.0f / (524288.0f * 32767.0f))
#define C1E (65536.0f / (524288.0f * 4096.0f))    // step 0 (Sh=4096) = 2^-15
#define C2E (  256.0f / (524288.0f * 4096.0f))    //                  = 2^-23

// ---------------------------------------------------------------------------
// Transpose W_ih (2048 x 512) -> W_ihT (512 x 2048): one-hot gather rows.
// ---------------------------------------------------------------------------
__global__ __launch_bounds__(256) void k_transpose(const float* __restrict__ in,
                                                   float* __restrict__ out){
  __shared__ float tile[32][33];
  const int tx = threadIdx.x, ty = threadIdx.y;
  const int v0 = blockIdx.x * 32, n0 = blockIdx.y * 32;
#pragma unroll
  for(int i=0;i<4;i++)
    tile[ty+i*8][tx] = in[(size_t)(n0+ty+i*8)*Vd + v0+tx];
  __syncthreads();
#pragma unroll
  for(int i=0;i<4;i++)
    out[(size_t)(v0+ty+i*8)*G4 + n0+tx] = tile[tx][ty+i*8];
}

// ---------------------------------------------------------------------------
// Split fp32 -> int16 fixed-point -> i8 planes
// ---------------------------------------------------------------------------
__global__ __launch_bounds__(256) void k_split_i8(const float* __restrict__ src,
                                                  signed char* __restrict__ pa,
                                                  signed char* __restrict__ pb,
                                                  float S, int n){
  const int i = blockIdx.x*256 + threadIdx.x;
  if(i < n){
    signed char a, b;
    i16split(src[i], S, a, b);
    pa[i] = a; pb[i] = b;
  }
}

// ---------------------------------------------------------------------------
// Kernel A0 (step 0): i8 LSTM step from quantized enc_h (Sh=4096).
// Same structure as k_lstm_i8 but no merge prologue and no one-hot gather.
// ---------------------------------------------------------------------------
__global__ __launch_bounds__(256, 2) void k_lstm_i8_first(
    const signed char* __restrict__ hA, const signed char* __restrict__ hB,
    const float* __restrict__ cin,
    signed char* __restrict__ hoA, signed char* __restrict__ hoB,
    float* __restrict__ cout,
    const signed char* __restrict__ WA, const signed char* __restrict__ WB,
    const float* __restrict__ bih, const float* __restrict__ bhh)
{
  __shared__ unsigned char lds[2][32768];
  const int tid = threadIdx.x;
  const int wave = tid >> 6, lane = tid & 63;
  const int mb = blockIdx.x * 128;
  const int jb = blockIdx.y * 32;
  const int b_wave = (wave & 1) * 64;
  const int j_wave = (wave >> 1) * 16;
  const int fr = lane & 15, q = lane >> 4;
  const int lr = lane >> 2, jj = lane & 3;

  auto stage = [&](int k0, int bsel){
    unsigned char* Wa = lds[bsel];
    unsigned char* Wb = lds[bsel] + 8192;
    unsigned char* Ha = lds[bsel] + 16384;
    unsigned char* Hb = lds[bsel] + 24576;
#pragma unroll
    for(int p=0;p<2;p++){
      const int s = wave*2 + p;
      const int r = s*16 + lr;
      const int j = jj ^ ((r >> 1) & 3);
      const size_t ka = (size_t)k0 + j*16;
      const size_t wrow = (size_t)((r >> 5)*Hd + jb + (r & 31));
      gl_lds16(WA + wrow*Hd + ka, &Wa[s*1024]);
      gl_lds16(WB + wrow*Hd + ka, &Wb[s*1024]);
      gl_lds16(hA + (size_t)(mb + r)*Hd + ka, &Ha[s*1024]);
      gl_lds16(hB + (size_t)(mb + r)*Hd + ka, &Hb[s*1024]);
    }
  };

  stage(0, 0);

  int4v acc1[4][4], acc2[4][4];
#pragma unroll
  for(int g=0;g<4;g++)
#pragma unroll
    for(int bt=0;bt<4;bt++){
      acc1[g][bt] = (int4v){0,0,0,0};
      acc2[g][bt] = (int4v){0,0,0,0};
    }

  for(int kc=0; kc<8; kc++){
    __syncthreads();
    if(kc < 7) stage((kc+1)*64, (kc+1)&1);

    const unsigned char* Wa = lds[kc&1];
    const unsigned char* Wb = lds[kc&1] + 8192;
    const unsigned char* Ha = lds[kc&1] + 16384;
    const unsigned char* Hb = lds[kc&1] + 24576;

    int4v wa[4], wb[4], hf[4], lf[4];
#pragma unroll
    for(int g=0;g<4;g++){
      const int r = g*32 + j_wave + fr;
      const int off = r*64 + ((q ^ ((r >> 1) & 3)) << 4);
      wa[g] = *(const int4v*)&Wa[off];
      wb[g] = *(const int4v*)&Wb[off];
    }
#pragma unroll
    for(int bt=0;bt<4;bt++){
      const int r = b_wave + bt*16 + fr;
      const int off = r*64 + ((q ^ ((r >> 1) & 3)) << 4);
      hf[bt] = *(const int4v*)&Ha[off];
      lf[bt] = *(const int4v*)&Hb[off];
    }
#pragma unroll
    for(int g=0;g<4;g++)
#pragma unroll
      for(int bt=0;bt<4;bt++){
        acc1[g][bt] = __builtin_amdgcn_mfma_i32_16x16x64_i8(wa[g], hf[bt], acc1[g][bt], 0,0,0);
        acc2[g][bt] = __builtin_amdgcn_mfma_i32_16x16x64_i8(wa[g], lf[bt], acc2[g][bt], 0,0,0);
        acc2[g][bt] = __builtin_amdgcn_mfma_i32_16x16x64_i8(wb[g], hf[bt], acc2[g][bt], 0,0,0);
      }
  }

  const int j0 = jb + j_wave + q*4;
  float bsum[4][4];
#pragma unroll
  for(int g=0;g<4;g++){
    float4 a = *(const float4*)&bih[g*Hd + j0];
    float4 b = *(const float4*)&bhh[g*Hd + j0];
    bsum[g][0]=a.x+b.x; bsum[g][1]=a.y+b.y; bsum[g][2]=a.z+b.z; bsum[g][3]=a.w+b.w;
  }
#pragma unroll
  for(int bt=0;bt<4;bt++){
    const int b = mb + b_wave + bt*16 + fr;
    const size_t idx = (size_t)b*Hd + j0;
    float gv[4][4];
#pragma unroll
    for(int g=0;g<4;g++)
#pragma unroll
      for(int r=0;r<4;r++)
        gv[g][r] = fmaf(C1E, (float)acc1[g][bt][r],
                   fmaf(C2E, (float)acc2[g][bt][r], bsum[g][r]));
    float co[4];
    *(float4*)co = *(const float4*)&cin[idx];
    float cn[4];
    signed char a4[4], b4[4];
#pragma unroll
    for(int r=0;r<4;r++){
      const float I = sigm_f(gv[0][r]);
      const float F = sigm_f(gv[1][r]);
      const float G = tanh_f(gv[2][r]);
      const float O = sigm_f(gv[3][r]);
      cn[r] = F*co[r] + I*G;
      const float hn = O*tanh_f(cn[r]);
      i16split(hn, 32767.0f, a4[r], b4[r]);
    }
    *(float4*)&cout[idx] = *(float4*)cn;
    *(char4*)&hoA[idx] = *(char4*)a4;
    *(char4*)&hoB[idx] = *(char4*)b4;
  }
}

// ---------------------------------------------------------------------------
// Kernel A (steps >=1): i8 LSTM step with fused prev-step merge (r9).
// Stats layout [slab][row] (r9 — write-coalesced in B, read-coalesced here).
// ---------------------------------------------------------------------------
__global__ __launch_bounds__(256, 2) void k_lstm_i8(
    const signed char* __restrict__ hA, const signed char* __restrict__ hB,
    const float* __restrict__ cin,
    signed char* __restrict__ hoA, signed char* __restrict__ hoB,
    float* __restrict__ cout,
    const signed char* __restrict__ WA, const signed char* __restrict__ WB,
    const float* __restrict__ WihT, const float* __restrict__ bih,
    const float* __restrict__ bhh,
    const float* __restrict__ statM, const float* __restrict__ statS,
    const int* __restrict__ statI,
    float* __restrict__ msg, float* __restrict__ masks_out,
    float* __restrict__ lp_out, float* __restrict__ lpbuf,
    float* __restrict__ mbuf, int prev)
{
  __shared__ unsigned char lds[2][32768];
  __shared__ int gIs[128];
  const int tid = threadIdx.x;
  const int wave = tid >> 6, lane = tid & 63;
  const int mb = blockIdx.x * 128;
  const int jb = blockIdx.y * 32;
  const int b_wave = (wave & 1) * 64;
  const int j_wave = (wave >> 1) * 16;
  const int fr = lane & 15, q = lane >> 4;
  const int lr = lane >> 2, jj = lane & 3;

  auto stage = [&](int k0, int bsel){
    unsigned char* Wa = lds[bsel];
    unsigned char* Wb = lds[bsel] + 8192;
    unsigned char* Ha = lds[bsel] + 16384;
    unsigned char* Hb = lds[bsel] + 24576;
#pragma unroll
    for(int p=0;p<2;p++){
      const int s = wave*2 + p;
      const int r = s*16 + lr;
      const int j = jj ^ ((r >> 1) & 3);
      const size_t ka = (size_t)k0 + j*16;
      const size_t wrow = (size_t)((r >> 5)*Hd + jb + (r & 31));
      gl_lds16(WA + wrow*Hd + ka, &Wa[s*1024]);
      gl_lds16(WB + wrow*Hd + ka, &Wb[s*1024]);
      gl_lds16(hA + (size_t)(mb + r)*Hd + ka, &Ha[s*1024]);
      gl_lds16(hB + (size_t)(mb + r)*Hd + ka, &Hb[s*1024]);
    }
  };

  stage(0, 0);   // async staging in flight during merge prologue

  // ---- merge prologue: prev-step stats -> gi per row (+ scalar outputs)
  if(tid < 128){
    const int row = mb + tid;
    float gm = statM[row]; int gi = statI[row];
#pragma unroll
    for(int s=1;s<NSLAB;s++){
      const float m = statM[(size_t)s*Bsz + row];
      if(m > gm){ gm = m; gi = statI[(size_t)s*Bsz + row]; }
    }
    if(blockIdx.y == 0){
      float tot = 0.0f;
#pragma unroll
      for(int s=0;s<NSLAB;s++)
        tot += statS[(size_t)s*Bsz + row] * __expf(statM[(size_t)s*Bsz + row] - gm);
      const float logp = -__logf(tot);
      const float mo  = (prev == 0) ? 1.0f : mbuf[row];
      const float lpo = (prev == 0) ? 0.0f : lpbuf[row];
      const float lpn = lpo + logp * mo;
      masks_out[(size_t)prev * Bsz + row] = mo;
      lp_out[row] = lpn;
      lpbuf[row]  = lpn;
      mbuf[row]   = mo * ((gi == Vd-1) ? 0.0f : 1.0f);
    }
    gIs[tid] = gi;
  }
  __syncthreads();

  // one-hot msg slice: this block writes cols [jb, jb+32) of prev-step msg
  {
    const int r  = tid >> 1;
    const int c0 = jb + (tid & 1) * 16;
    const int gi = gIs[r];
    float* mrow = msg + ((size_t)prev * Bsz + mb + r) * Vd;
#pragma unroll
    for(int i=0;i<4;i++){
      const int c = c0 + i*4;
      float4 v;
      v.x = (c   == gi) ? 1.0f : 0.0f;
      v.y = (c+1 == gi) ? 1.0f : 0.0f;
      v.z = (c+2 == gi) ? 1.0f : 0.0f;
      v.w = (c+3 == gi) ? 1.0f : 0.0f;
      *(float4*)&mrow[c] = v;
    }
  }

  int xid[4];
#pragma unroll
  for(int bt=0;bt<4;bt++)
    xid[bt] = gIs[b_wave + bt*16 + fr];

  int4v acc1[4][4], acc2[4][4];
#pragma unroll
  for(int g=0;g<4;g++)
#pragma unroll
    for(int bt=0;bt<4;bt++){
      acc1[g][bt] = (int4v){0,0,0,0};
      acc2[g][bt] = (int4v){0,0,0,0};
    }

  for(int kc=0; kc<8; kc++){
    __syncthreads();
    if(kc < 7) stage((kc+1)*64, (kc+1)&1);

    const unsigned char* Wa = lds[kc&1];
    const unsigned char* Wb = lds[kc&1] + 8192;
    const unsigned char* Ha = lds[kc&1] + 16384;
    const unsigned char* Hb = lds[kc&1] + 24576;

    int4v wa[4], wb[4], hf[4], lf[4];
#pragma unroll
    for(int g=0;g<4;g++){
      const int r = g*32 + j_wave + fr;
      const int off = r*64 + ((q ^ ((r >> 1) & 3)) << 4);
      wa[g] = *(const int4v*)&Wa[off];
      wb[g] = *(const int4v*)&Wb[off];
    }
#pragma unroll
    for(int bt=0;bt<4;bt++){
      const int r = b_wave + bt*16 + fr;
      const int off = r*64 + ((q ^ ((r >> 1) & 3)) << 4);
      hf[bt] = *(const int4v*)&Ha[off];
      lf[bt] = *(const int4v*)&Hb[off];
    }
#pragma unroll
    for(int g=0;g<4;g++)
#pragma unroll
      for(int bt=0;bt<4;bt++){
        acc1[g][bt] = __builtin_amdgcn_mfma_i32_16x16x64_i8(wa[g], hf[bt], acc1[g][bt], 0,0,0);
        acc2[g][bt] = __builtin_amdgcn_mfma_i32_16x16x64_i8(wa[g], lf[bt], acc2[g][bt], 0,0,0);
        acc2[g][bt] = __builtin_amdgcn_mfma_i32_16x16x64_i8(wb[g], hf[bt], acc2[g][bt], 0,0,0);
      }
  }

  const int j0 = jb + j_wave + q*4;
  float bsum[4][4];
#pragma unroll
  for(int g=0;g<4;g++){
    float4 a = *(const float4*)&bih[g*Hd + j0];
    float4 b = *(const float4*)&bhh[g*Hd + j0];
    bsum[g][0]=a.x+b.x; bsum[g][1]=a.y+b.y; bsum[g][2]=a.z+b.z; bsum[g][3]=a.w+b.w;
  }
#pragma unroll
  for(int bt=0;bt<4;bt++){
    const int b = mb + b_wave + bt*16 + fr;
    const size_t idx = (size_t)b*Hd + j0;
    float gv[4][4];
#pragma unroll
    for(int g=0;g<4;g++)
#pragma unroll
      for(int r=0;r<4;r++)
        gv[g][r] = fmaf(C1I, (float)acc1[g][bt][r],
                   fmaf(C2I, (float)acc2[g][bt][r], bsum[g][r]));
    {
      const float* grow = WihT + (size_t)xid[bt]*G4 + j0;
#pragma unroll
      for(int g=0;g<4;g++){
        float4 x = *(const float4*)&grow[g*Hd];
        gv[g][0]+=x.x; gv[g][1]+=x.y; gv[g][2]+=x.z; gv[g][3]+=x.w;
      }
    }
    float co[4];
    *(float4*)co = *(const float4*)&cin[idx];
    float cn[4];
    signed char a4[4], b4[4];
#pragma unroll
    for(int r=0;r<4;r++){
      const float I = sigm_f(gv[0][r]);
      const float F = sigm_f(gv[1][r]);
      const float G = tanh_f(gv[2][r]);
      const float O = sigm_f(gv[3][r]);
      cn[r] = F*co[r] + I*G;
      const float hn = O*tanh_f(cn[r]);
      i16split(hn, 32767.0f, a4[r], b4[r]);
    }
    *(float4*)&cout[idx] = *(float4*)cn;
    *(char4*)&hoA[idx] = *(char4*)a4;
    *(char4*)&hoB[idx] = *(char4*)b4;
  }
}

// ---------------------------------------------------------------------------
// Kernel B: logits STATS ONLY (r9).  128x64 tile, grid (64,8), dbuf LDS.
// Stats written [slab][row] (write-coalesced).
// ---------------------------------------------------------------------------
__global__ __launch_bounds__(256, 2) void k_logits_i8(
    const signed char* __restrict__ hA, const signed char* __restrict__ hB,
    const signed char* __restrict__ WoA, const signed char* __restrict__ WoB,
    const float* __restrict__ bout,
    float* __restrict__ statM, float* __restrict__ statS, int* __restrict__ statI)
{
  __shared__ unsigned char lds[2][24576];   // Ha 8K | Hb 8K | Wa 4K | Wb 4K
  const int tid = threadIdx.x;
  const int wave = tid >> 6, lane = tid & 63;
  const int mb = blockIdx.x * 128;
  const int vb = blockIdx.y * 64;
  const int m_wave = (wave & 1) * 64;
  const int n_wave = (wave >> 1) * 32;
  const int fr = lane & 15, q = lane >> 4;
  const int lr = lane >> 2, jj = lane & 3;

  auto stage = [&](int k0, int bsel){
    unsigned char* Ha = lds[bsel];
    unsigned char* Hb = lds[bsel] + 8192;
    unsigned char* Wa = lds[bsel] + 16384;
    unsigned char* Wb = lds[bsel] + 20480;
#pragma unroll
    for(int p=0;p<2;p++){
      const int s = wave*2 + p;
      const int r = s*16 + lr;
      const int j = jj ^ ((r >> 1) & 3);
      const size_t ka = (size_t)k0 + j*16;
      gl_lds16(hA + (size_t)(mb + r)*Hd + ka, &Ha[s*1024]);
      gl_lds16(hB + (size_t)(mb + r)*Hd + ka, &Hb[s*1024]);
    }
    {
      const int r = wave*16 + lr;
      const int j = jj ^ ((r >> 1) & 3);
      const size_t ka = (size_t)k0 + j*16;
      gl_lds16(WoA + (size_t)(vb + r)*Hd + ka, &Wa[wave*1024]);
      gl_lds16(WoB + (size_t)(vb + r)*Hd + ka, &Wb[wave*1024]);
    }
  };

  stage(0, 0);

  int4v acc1[2][4], acc2[2][4];
#pragma unroll
  for(int nt=0;nt<2;nt++)
#pragma unroll
    for(int mt=0;mt<4;mt++){
      acc1[nt][mt] = (int4v){0,0,0,0};
      acc2[nt][mt] = (int4v){0,0,0,0};
    }

  for(int kc=0; kc<8; kc++){
    __syncthreads();
    if(kc < 7) stage((kc+1)*64, (kc+1)&1);

    const unsigned char* Ha = lds[kc&1];
    const unsigned char* Hb = lds[kc&1] + 8192;
    const unsigned char* Wa = lds[kc&1] + 16384;
    const unsigned char* Wb = lds[kc&1] + 20480;

    int4v ah[4], al[4], bh[2], bl[2];
#pragma unroll
    for(int mt=0;mt<4;mt++){
      const int r = m_wave + mt*16 + fr;
      const int off = r*64 + ((q ^ ((r >> 1) & 3)) << 4);
      ah[mt] = *(const int4v*)&Ha[off];
      al[mt] = *(const int4v*)&Hb[off];
    }
#pragma unroll
    for(int nt=0;nt<2;nt++){
      const int r = n_wave + nt*16 + fr;
      const int off = r*64 + ((q ^ ((r >> 1) & 3)) << 4);
      bh[nt] = *(const int4v*)&Wa[off];
      bl[nt] = *(const int4v*)&Wb[off];
    }
#pragma unroll
    for(int nt=0;nt<2;nt++)
#pragma unroll
      for(int mt=0;mt<4;mt++){
        acc1[nt][mt] = __builtin_amdgcn_mfma_i32_16x16x64_i8(ah[mt], bh[nt], acc1[nt][mt], 0,0,0);
        acc2[nt][mt] = __builtin_amdgcn_mfma_i32_16x16x64_i8(ah[mt], bl[nt], acc2[nt][mt], 0,0,0);
        acc2[nt][mt] = __builtin_amdgcn_mfma_i32_16x16x64_i8(al[mt], bh[nt], acc2[nt][mt], 0,0,0);
      }
  }

  const int slab = blockIdx.y*2 + (wave >> 1);
  float bo[2];
  int vv[2];
#pragma unroll
  for(int nt=0;nt<2;nt++){
    vv[nt] = vb + n_wave + nt*16 + fr;
    bo[nt] = bout[vv[nt]];
  }
#pragma unroll
  for(int mt=0;mt<4;mt++){
#pragma unroll
    for(int reg=0;reg<4;reg++){
      float lg[2];
#pragma unroll
      for(int nt=0;nt<2;nt++)
        lg[nt] = fmaf(C1I, (float)acc1[nt][mt][reg],
                 fmaf(C2I, (float)acc2[nt][mt][reg], bo[nt]));
      float vmax = lg[0];
      int   imax = vv[0];
      if(lg[1] > vmax || (lg[1] == vmax && vv[1] < imax)){ vmax = lg[1]; imax = vv[1]; }
#pragma unroll
      for(int off=1; off<16; off<<=1){
        const float vo = __shfl_xor(vmax, off);
        const int   io = __shfl_xor(imax, off);
        if(vo > vmax || (vo == vmax && io < imax)){ vmax = vo; imax = io; }
      }
      float s = __expf(lg[0] - vmax) + __expf(lg[1] - vmax);
#pragma unroll
      for(int off=1; off<16; off<<=1) s += __shfl_xor(s, off);
      if(fr == 0){
        const int m = mb + m_wave + mt*16 + q*4 + reg;
        statM[(size_t)slab*Bsz + m] = vmax;
        statS[(size_t)slab*Bsz + m] = s;
        statI[(size_t)slab*Bsz + m] = imax;
      }
    }
  }
}

// ---------------------------------------------------------------------------
// Kernel C (final step only): merge 16 slabs, write msg/masks/lp.
// ---------------------------------------------------------------------------
__global__ __launch_bounds__(256) void k_merge(
    const float* __restrict__ statM, const float* __restrict__ statS,
    const int* __restrict__ statI,
    float* __restrict__ msg, float* __restrict__ masks_out,
    float* __restrict__ lp_out, float* __restrict__ lpbuf,
    float* __restrict__ mbuf, int step)
{
  __shared__ int gI[32];
  const int tid = threadIdx.x;
  const int mb = blockIdx.x * 32;

  if(tid < 32){
    const int row = mb + tid;
    float gm = statM[row]; int gi = statI[row];
#pragma unroll
    for(int s=1;s<NSLAB;s++){
      const float m = statM[(size_t)s*Bsz + row];
      if(m > gm){ gm = m; gi = statI[(size_t)s*Bsz + row]; }
    }
    float tot = 0.0f;
#pragma unroll
    for(int s=0;s<NSLAB;s++)
      tot += statS[(size_t)s*Bsz + row] * __expf(statM[(size_t)s*Bsz + row] - gm);
    const float logp = -__logf(tot);
    const float mo  = mbuf[row];
    const float lpn = lpbuf[row] + logp * mo;
    masks_out[(size_t)step * Bsz + row] = mo;
    lp_out[row] = lpn;
    gI[tid] = gi;
  }
  __syncthreads();

  const int r  = tid >> 3;
  const int c8 = tid & 7;
  const int gi = gI[r];
  float* mrow = msg + ((size_t)step * Bsz + mb + r) * Vd;
#pragma unroll
  for(int i=0;i<16;i++){
    const int c = (i*8 + c8) * 4;
    float4 v;
    v.x = (c   == gi) ? 1.0f : 0.0f;
    v.y = (c+1 == gi) ? 1.0f : 0.0f;
    v.z = (c+2 == gi) ? 1.0f : 0.0f;
    v.w = (c+3 == gi) ? 1.0f : 0.0f;
    *(float4*)&mrow[c] = v;
  }
}

// ---------------------------------------------------------------------------
extern "C" void kernel_launch(void* const* d_in, const int* in_sizes, int n_in,
                              void* d_out, int out_size, void* d_ws, size_t ws_size,
                              hipStream_t stream) {
  const float* enc_h = (const float*)d_in[0];
  const float* enc_c = (const float*)d_in[1];
  const float* Wih   = (const float*)d_in[2];
  const float* Whh   = (const float*)d_in[3];
  const float* bih   = (const float*)d_in[4];
  const float* bhh   = (const float*)d_in[5];
  const float* Wout  = (const float*)d_in[6];
  const float* bout  = (const float*)d_in[7];

  float* out_msg   = (float*)d_out;                       // [16][8192][512]
  float* out_masks = out_msg + (size_t)Ld * Bsz * Vd;     // [16][1][8192]
  float* out_lp    = out_masks + (size_t)Ld * Bsz;        // [8192]

  char* ws = (char*)d_ws;
  float* WihT  = (float*)ws;          ws += (size_t)Vd * G4 * 4;           // 4 MB
  signed char* WhhA = (signed char*)ws; ws += (size_t)G4 * Hd;             // 1 MB
  signed char* WhhB = (signed char*)ws; ws += (size_t)G4 * Hd;             // 1 MB
  signed char* WoA  = (signed char*)ws; ws += (size_t)Vd * Hd;             // 256 KB
  signed char* WoB  = (signed char*)ws; ws += (size_t)Vd * Hd;             // 256 KB
  signed char* encA = (signed char*)ws; ws += (size_t)Bsz * Hd;            // 4 MB
  signed char* encB = (signed char*)ws; ws += (size_t)Bsz * Hd;            // 4 MB
  signed char* ha0  = (signed char*)ws; ws += (size_t)Bsz * Hd;            // 4 MB
  signed char* hb0  = (signed char*)ws; ws += (size_t)Bsz * Hd;
  signed char* ha1  = (signed char*)ws; ws += (size_t)Bsz * Hd;
  signed char* hb1  = (signed char*)ws; ws += (size_t)Bsz * Hd;
  float* cbuf   = (float*)ws;  ws += (size_t)Bsz * Hd * 4;                 // 16 MB
  float* statM  = (float*)ws;  ws += (size_t)NSLAB * Bsz * 4;              // 512 KB
  float* statS  = (float*)ws;  ws += (size_t)NSLAB * Bsz * 4;
  int*   statI  = (int*)ws;    ws += (size_t)NSLAB * Bsz * 4;
  float* lpbuf  = (float*)ws;  ws += (size_t)Bsz * 4;
  float* mbuf   = (float*)ws;  ws += (size_t)Bsz * 4;

  k_transpose<<<dim3(Vd/32, G4/32), dim3(32,8), 0, stream>>>(Wih, WihT);
  k_split_i8<<<(G4*Hd+255)/256, 256, 0, stream>>>(Whh, WhhA, WhhB, 524288.0f, G4*Hd);
  k_split_i8<<<(Vd*Hd+255)/256, 256, 0, stream>>>(Wout, WoA, WoB, 524288.0f, Vd*Hd);
  k_split_i8<<<(Bsz*Hd+255)/256, 256, 0, stream>>>(enc_h, encA, encB, 4096.0f, Bsz*Hd);

  for(int t=0; t<Ld; t++){
    signed char* haOut = (t & 1) ? ha1 : ha0;
    signed char* hbOut = (t & 1) ? hb1 : hb0;
    const signed char* haIn = (t & 1) ? ha0 : ha1;
    const signed char* hbIn = (t & 1) ? hb0 : hb1;

    if(t == 0){
      k_lstm_i8_first<<<dim3(Bsz/128, Hd/32), 256, 0, stream>>>(
          encA, encB, enc_c, haOut, hbOut, cbuf, WhhA, WhhB, bih, bhh);
    } else {
      k_lstm_i8<<<dim3(Bsz/128, Hd/32), 256, 0, stream>>>(
          haIn, hbIn, cbuf, haOut, hbOut, cbuf, WhhA, WhhB, WihT, bih, bhh,
          statM, statS, statI, out_msg, out_masks, out_lp, lpbuf, mbuf, t-1);
    }
    k_logits_i8<<<dim3(Bsz/128, Vd/64), 256, 0, stream>>>(
        haOut, hbOut, WoA, WoB, bout, statM, statS, statI);
  }
  k_merge<<<Bsz/32, 256, 0, stream>>>(statM, statS, statI,
                                      out_msg, out_masks, out_lp,
                                      lpbuf, mbuf, Ld-1);
}